// Round 1
// baseline (320.644 us; speedup 1.0000x reference)
//
#include <hip/hip_runtime.h>
#include <hip/hip_bf16.h>
#include <float.h>

// MixMIL fused kernel set.
// Shapes (fixed by setup_inputs): I=512000, Q=128, P=1, S=8 (C=8 channels), N=4000.
// d_in: x[I,Q] f32, beta_u[Q,1,8] f32, beta_z[Q,1,8] f32, i[I] int32 (sorted), n_bags (scalar)
// d_out: [N,1,8] f32.
//
// Algebra: eta = beta_z/b and out = b*(xmil-mean)/std. Since std scales linearly
// with the positive per-channel b, accumulating with raw beta_z (v = x.beta_z)
// gives xmil' = b*xmil, and b*(xmil'-mean')/std' == b*(xmil-mean)/std. So we
// never form eta; b only multiplies at the very end.

#define QDIM 128
#define C8 8

__device__ __forceinline__ void dot4(float& acc, const float4 a, const float4 b) {
    acc = fmaf(a.x, b.x, acc);
    acc = fmaf(a.y, b.y, acc);
    acc = fmaf(a.z, b.z, acc);
    acc = fmaf(a.w, b.w, acc);
}

// One block (64 threads = 1 wave) per bag. Online softmax + weighted sum, fused.
__global__ __launch_bounds__(64) void mixmil_bags(
    const float* __restrict__ x,
    const float* __restrict__ bu,
    const float* __restrict__ bz,
    const int*   __restrict__ seg,
    int I,
    float* __restrict__ xmil)  // [N,8]
{
    __shared__ float WT[16][QDIM];  // rows 0..7: beta_u^T, rows 8..15: beta_z^T

    const int n = blockIdx.x;
    const int t = threadIdx.x;

    // Stage transposed weights: WT[c][q] = bu[q*8+c], WT[8+c][q] = bz[q*8+c]
    for (int j = t; j < QDIM * C8; j += 64) {
        int q = j >> 3, s = j & 7;
        WT[s][q]     = bu[j];
        WT[8 + s][q] = bz[j];
    }

    // Bag range via binary search on sorted seg ids (redundant per thread, cheap).
    int lo = 0, h = I;
    while (lo < h) { int mid = (lo + h) >> 1; if (seg[mid] < n) lo = mid + 1; else h = mid; }
    int lo2 = lo, h2 = I;
    while (lo2 < h2) { int mid = (lo2 + h2) >> 1; if (seg[mid] < n + 1) lo2 = mid + 1; else h2 = mid; }
    const int hi = lo2;

    __syncthreads();

    // Per-thread online softmax state per channel: m (max), l (sum e), a (sum e*v)
    float mM[8], lL[8], aA[8];
#pragma unroll
    for (int c = 0; c < 8; ++c) { mM[c] = -1e30f; lL[c] = 0.f; aA[c] = 0.f; }

    // Each thread processes instances lo+t, lo+t+64, ... two at a time so the
    // LDS weight broadcasts amortize over 2 instances.
    for (int k = lo + t; k < hi; k += 128) {
        const bool two = (k + 64) < hi;
        const float* xr1 = x + (long)k * QDIM;
        const float* xr2 = x + (long)(two ? (k + 64) : k) * QDIM;

        float du1[8], dv1[8], du2[8], dv2[8];
#pragma unroll
        for (int c = 0; c < 8; ++c) { du1[c] = dv1[c] = du2[c] = dv2[c] = 0.f; }

        for (int q0 = 0; q0 < QDIM; q0 += 4) {
            const float4 xa = *(const float4*)(xr1 + q0);
            const float4 xb = *(const float4*)(xr2 + q0);
#pragma unroll
            for (int c = 0; c < 8; ++c) {
                const float4 wu = *(const float4*)&WT[c][q0];
                const float4 wz = *(const float4*)&WT[8 + c][q0];
                dot4(du1[c], xa, wu);
                dot4(dv1[c], xa, wz);
                dot4(du2[c], xb, wu);
                dot4(dv2[c], xb, wz);
            }
        }

        // Online update, instance 1 then (if valid) instance 2.
#pragma unroll
        for (int c = 0; c < 8; ++c) {
            {
                float u = du1[c], v = dv1[c];
                float nm = fmaxf(mM[c], u);
                float sc = __expf(mM[c] - nm);
                float p  = __expf(u - nm);
                lL[c] = lL[c] * sc + p;
                aA[c] = aA[c] * sc + p * v;
                mM[c] = nm;
            }
            if (two) {
                float u = du2[c], v = dv2[c];
                float nm = fmaxf(mM[c], u);
                float sc = __expf(mM[c] - nm);
                float p  = __expf(u - nm);
                lL[c] = lL[c] * sc + p;
                aA[c] = aA[c] * sc + p * v;
                mM[c] = nm;
            }
        }
    }

    // Butterfly merge of online states across the 64 lanes.
    for (int off = 32; off; off >>= 1) {
#pragma unroll
        for (int c = 0; c < 8; ++c) {
            float m2 = __shfl_xor(mM[c], off);
            float l2 = __shfl_xor(lL[c], off);
            float a2 = __shfl_xor(aA[c], off);
            float nm = fmaxf(mM[c], m2);
            float s1 = __expf(mM[c] - nm);
            float s2 = __expf(m2 - nm);
            lL[c] = lL[c] * s1 + l2 * s2;
            aA[c] = aA[c] * s1 + a2 * s2;
            mM[c] = nm;
        }
    }

    if (t == 0) {
        const bool nonempty = hi > lo;
#pragma unroll
        for (int c = 0; c < 8; ++c)
            xmil[(size_t)n * 8 + c] = nonempty ? (aA[c] / lL[c]) : 0.f;
    }
}

// Single block: per-channel mean/var (ddof=1) of xmil over bags, plus b = rms(beta_z).
// Deterministic (no atomics). stats layout: [0..7]=b, [8..15]=mean, [16..23]=rstd.
__global__ __launch_bounds__(256) void mixmil_stats(
    const float* __restrict__ xmil,
    const float* __restrict__ bz,
    int N,
    float* __restrict__ stats)
{
    double s[8], qq[8];
    float t2[8];
#pragma unroll
    for (int c = 0; c < 8; ++c) { s[c] = 0.0; qq[c] = 0.0; t2[c] = 0.f; }

    for (int r = threadIdx.x; r < N; r += 256) {
        const float* row = xmil + (size_t)r * 8;
#pragma unroll
        for (int c = 0; c < 8; ++c) {
            float v = row[c];
            s[c] += v;
            qq[c] += (double)v * (double)v;
        }
    }
    for (int r = threadIdx.x; r < QDIM; r += 256) {
        const float* row = bz + (size_t)r * 8;
#pragma unroll
        for (int c = 0; c < 8; ++c) { float v = row[c]; t2[c] = fmaf(v, v, t2[c]); }
    }

    // wave reduce (width 64)
    for (int off = 32; off; off >>= 1) {
#pragma unroll
        for (int c = 0; c < 8; ++c) {
            s[c]  += __shfl_xor(s[c], off);
            qq[c] += __shfl_xor(qq[c], off);
            t2[c] += __shfl_xor(t2[c], off);
        }
    }

    __shared__ double S[4][8], QQ[4][8];
    __shared__ float T2[4][8];
    const int w = threadIdx.x >> 6;
    if ((threadIdx.x & 63) == 0) {
#pragma unroll
        for (int c = 0; c < 8; ++c) { S[w][c] = s[c]; QQ[w][c] = qq[c]; T2[w][c] = t2[c]; }
    }
    __syncthreads();
    if (threadIdx.x == 0) {
#pragma unroll
        for (int c = 0; c < 8; ++c) {
            double ss = S[0][c] + S[1][c] + S[2][c] + S[3][c];
            double qs = QQ[0][c] + QQ[1][c] + QQ[2][c] + QQ[3][c];
            float  tt = T2[0][c] + T2[1][c] + T2[2][c] + T2[3][c];
            double mean = ss / (double)N;
            double var  = (qs - ss * ss / (double)N) / (double)(N - 1);
            stats[c]      = sqrtf(tt / (float)QDIM);   // b
            stats[8 + c]  = (float)mean;
            stats[16 + c] = (float)(1.0 / sqrt(var));  // rstd
        }
    }
}

__global__ void mixmil_out(
    const float* __restrict__ xmil,
    const float* __restrict__ stats,
    int total,
    float* __restrict__ out)
{
    int e = blockIdx.x * blockDim.x + threadIdx.x;
    if (e >= total) return;
    int c = e & 7;
    out[e] = stats[c] * (xmil[e] - stats[8 + c]) * stats[16 + c];
}

extern "C" void kernel_launch(void* const* d_in, const int* in_sizes, int n_in,
                              void* d_out, int out_size, void* d_ws, size_t ws_size,
                              hipStream_t stream) {
    const float* x  = (const float*)d_in[0];
    const float* bu = (const float*)d_in[1];
    const float* bz = (const float*)d_in[2];
    const int*   sg = (const int*)d_in[3];   // sorted bag ids (int32: jax x64 off)

    const int I = in_sizes[0] / QDIM;        // 512000
    const int N = out_size / C8;             // 4000 bags

    float* xmil  = (float*)d_ws;             // [N,8]
    float* stats = xmil + (size_t)N * C8;    // 24 floats

    mixmil_bags<<<N, 64, 0, stream>>>(x, bu, bz, sg, I, xmil);
    mixmil_stats<<<1, 256, 0, stream>>>(xmil, bz, N, stats);

    const int total = N * C8;
    mixmil_out<<<(total + 255) / 256, 256, 0, stream>>>(
        xmil, stats, total, (float*)d_out);
}

// Round 2
// 141.449 us; speedup vs baseline: 2.2669x; 2.2669x over previous
//
#include <hip/hip_runtime.h>
#include <hip/hip_bf16.h>
#include <float.h>

// MixMIL fused kernel set.
// Shapes (fixed by setup_inputs): I=512000, Q=128, P=1, S=8 (C=8 channels), N=4000.
// d_in: x[I,Q] f32, beta_u[Q,1,8] f32, beta_z[Q,1,8] f32, i[I] int32 (sorted), n_bags
// d_out: [N,1,8] f32.
//
// Algebra: eta = beta_z/b and out = b*(xmil-mean)/std. std scales linearly with
// the positive per-channel b, so accumulating with raw beta_z (v = x.beta_z)
// gives xmil' = b*xmil and b*(xmil'-mean')/std' == b*(xmil-mean)/std. We never
// form eta; b multiplies only at the very end.
//
// R1 change vs R0: 64B-granular per-lane global loads (4 consecutive float4 per
// row per iteration) to kill the 3.4x L1-thrash over-fetch; q-major LDS staging
// to kill the 8-way bank-conflict writes.

#define QDIM 128
#define C8 8

__device__ __forceinline__ void dot4(float& acc, const float4 a, const float4 b) {
    acc = fmaf(a.x, b.x, acc);
    acc = fmaf(a.y, b.y, acc);
    acc = fmaf(a.z, b.z, acc);
    acc = fmaf(a.w, b.w, acc);
}

// One block (64 threads = 1 wave) per bag. Online softmax + weighted sum, fused.
__global__ __launch_bounds__(64) void mixmil_bags(
    const float* __restrict__ x,
    const float* __restrict__ bu,
    const float* __restrict__ bz,
    const int*   __restrict__ seg,
    int I,
    float* __restrict__ xmil)  // [N,8]
{
    __shared__ float WT[16][QDIM];  // rows 0..7: beta_u^T, rows 8..15: beta_z^T

    const int n = blockIdx.x;
    const int t = threadIdx.x;

    // Conflict-free staging: lane t writes consecutive q for fixed s
    // (banks 0..31, 2 lanes/bank = free).
    for (int j = t; j < QDIM * 16; j += 64) {
        int s = j >> 7, q = j & 127;
        WT[s][q] = (s < 8) ? bu[q * 8 + s] : bz[q * 8 + (s - 8)];
    }

    // Bag range via binary search on sorted seg ids (redundant per thread, cheap).
    int lo = 0, h = I;
    while (lo < h) { int mid = (lo + h) >> 1; if (seg[mid] < n) lo = mid + 1; else h = mid; }
    int lo2 = lo, h2 = I;
    while (lo2 < h2) { int mid = (lo2 + h2) >> 1; if (seg[mid] < n + 1) lo2 = mid + 1; else h2 = mid; }
    const int hi = lo2;

    __syncthreads();

    // Per-thread online softmax state per channel: m (max), l (sum e), a (sum e*v)
    float mM[8], lL[8], aA[8];
#pragma unroll
    for (int c = 0; c < 8; ++c) { mM[c] = -1e30f; lL[c] = 0.f; aA[c] = 0.f; }

    // Each thread processes instances lo+t, lo+t+64 (2 in flight so the LDS
    // weight broadcasts amortize over 2 rows).
    for (int k = lo + t; k < hi; k += 128) {
        const bool two = (k + 64) < hi;
        const float* xr1 = x + (long)k * QDIM;
        const float* xr2 = x + (long)(two ? (k + 64) : k) * QDIM;

        float du1[8], dv1[8], du2[8], dv2[8];
#pragma unroll
        for (int c = 0; c < 8; ++c) { du1[c] = dv1[c] = du2[c] = dv2[c] = 0.f; }

#pragma unroll 1
        for (int q0 = 0; q0 < QDIM; q0 += 16) {
            // 64B-granular per-lane loads: 4 consecutive float4 per row, so
            // every touched cache line is fully consumed immediately.
            float4 xa[4], xb[4];
#pragma unroll
            for (int j = 0; j < 4; ++j) {
                xa[j] = *(const float4*)(xr1 + q0 + 4 * j);
                xb[j] = *(const float4*)(xr2 + q0 + 4 * j);
            }
#pragma unroll
            for (int c = 0; c < 8; ++c) {
#pragma unroll
                for (int j = 0; j < 4; ++j) {
                    const float4 wu = *(const float4*)&WT[c][q0 + 4 * j];      // broadcast
                    const float4 wz = *(const float4*)&WT[8 + c][q0 + 4 * j];  // broadcast
                    dot4(du1[c], xa[j], wu);
                    dot4(dv1[c], xa[j], wz);
                    dot4(du2[c], xb[j], wu);
                    dot4(dv2[c], xb[j], wz);
                }
            }
        }

        // Online update, instance 1 then (if valid) instance 2.
#pragma unroll
        for (int c = 0; c < 8; ++c) {
            {
                float u = du1[c], v = dv1[c];
                float nm = fmaxf(mM[c], u);
                float sc = __expf(mM[c] - nm);
                float p  = __expf(u - nm);
                lL[c] = lL[c] * sc + p;
                aA[c] = aA[c] * sc + p * v;
                mM[c] = nm;
            }
            if (two) {
                float u = du2[c], v = dv2[c];
                float nm = fmaxf(mM[c], u);
                float sc = __expf(mM[c] - nm);
                float p  = __expf(u - nm);
                lL[c] = lL[c] * sc + p;
                aA[c] = aA[c] * sc + p * v;
                mM[c] = nm;
            }
        }
    }

    // Butterfly merge of online states across the 64 lanes.
    for (int off = 32; off; off >>= 1) {
#pragma unroll
        for (int c = 0; c < 8; ++c) {
            float m2 = __shfl_xor(mM[c], off);
            float l2 = __shfl_xor(lL[c], off);
            float a2 = __shfl_xor(aA[c], off);
            float nm = fmaxf(mM[c], m2);
            float s1 = __expf(mM[c] - nm);
            float s2 = __expf(m2 - nm);
            lL[c] = lL[c] * s1 + l2 * s2;
            aA[c] = aA[c] * s1 + a2 * s2;
            mM[c] = nm;
        }
    }

    if (t == 0) {
        const bool nonempty = hi > lo;
#pragma unroll
        for (int c = 0; c < 8; ++c)
            xmil[(size_t)n * 8 + c] = nonempty ? (aA[c] / lL[c]) : 0.f;
    }
}

// Single block: per-channel mean/var (ddof=1) of xmil over bags, plus b = rms(beta_z).
// Deterministic (no atomics). stats layout: [0..7]=b, [8..15]=mean, [16..23]=rstd.
__global__ __launch_bounds__(256) void mixmil_stats(
    const float* __restrict__ xmil,
    const float* __restrict__ bz,
    int N,
    float* __restrict__ stats)
{
    double s[8], qq[8];
    float t2[8];
#pragma unroll
    for (int c = 0; c < 8; ++c) { s[c] = 0.0; qq[c] = 0.0; t2[c] = 0.f; }

    for (int r = threadIdx.x; r < N; r += 256) {
        const float* row = xmil + (size_t)r * 8;
#pragma unroll
        for (int c = 0; c < 8; ++c) {
            float v = row[c];
            s[c] += v;
            qq[c] += (double)v * (double)v;
        }
    }
    for (int r = threadIdx.x; r < QDIM; r += 256) {
        const float* row = bz + (size_t)r * 8;
#pragma unroll
        for (int c = 0; c < 8; ++c) { float v = row[c]; t2[c] = fmaf(v, v, t2[c]); }
    }

    // wave reduce (width 64)
    for (int off = 32; off; off >>= 1) {
#pragma unroll
        for (int c = 0; c < 8; ++c) {
            s[c]  += __shfl_xor(s[c], off);
            qq[c] += __shfl_xor(qq[c], off);
            t2[c] += __shfl_xor(t2[c], off);
        }
    }

    __shared__ double S[4][8], QQ[4][8];
    __shared__ float T2[4][8];
    const int w = threadIdx.x >> 6;
    if ((threadIdx.x & 63) == 0) {
#pragma unroll
        for (int c = 0; c < 8; ++c) { S[w][c] = s[c]; QQ[w][c] = qq[c]; T2[w][c] = t2[c]; }
    }
    __syncthreads();
    if (threadIdx.x == 0) {
#pragma unroll
        for (int c = 0; c < 8; ++c) {
            double ss = S[0][c] + S[1][c] + S[2][c] + S[3][c];
            double qs = QQ[0][c] + QQ[1][c] + QQ[2][c] + QQ[3][c];
            float  tt = T2[0][c] + T2[1][c] + T2[2][c] + T2[3][c];
            double mean = ss / (double)N;
            double var  = (qs - ss * ss / (double)N) / (double)(N - 1);
            stats[c]      = sqrtf(tt / (float)QDIM);   // b
            stats[8 + c]  = (float)mean;
            stats[16 + c] = (float)(1.0 / sqrt(var));  // rstd
        }
    }
}

__global__ void mixmil_out(
    const float* __restrict__ xmil,
    const float* __restrict__ stats,
    int total,
    float* __restrict__ out)
{
    int e = blockIdx.x * blockDim.x + threadIdx.x;
    if (e >= total) return;
    int c = e & 7;
    out[e] = stats[c] * (xmil[e] - stats[8 + c]) * stats[16 + c];
}

extern "C" void kernel_launch(void* const* d_in, const int* in_sizes, int n_in,
                              void* d_out, int out_size, void* d_ws, size_t ws_size,
                              hipStream_t stream) {
    const float* x  = (const float*)d_in[0];
    const float* bu = (const float*)d_in[1];
    const float* bz = (const float*)d_in[2];
    const int*   sg = (const int*)d_in[3];   // sorted bag ids (int32)

    const int I = in_sizes[0] / QDIM;        // 512000
    const int N = out_size / C8;             // 4000 bags

    float* xmil  = (float*)d_ws;             // [N,8]
    float* stats = xmil + (size_t)N * C8;    // 24 floats

    mixmil_bags<<<N, 64, 0, stream>>>(x, bu, bz, sg, I, xmil);
    mixmil_stats<<<1, 256, 0, stream>>>(xmil, bz, N, stats);

    const int total = N * C8;
    mixmil_out<<<(total + 255) / 256, 256, 0, stream>>>(
        xmil, stats, total, (float*)d_out);
}

// Round 3
// 140.659 us; speedup vs baseline: 2.2796x; 1.0056x over previous
//
#include <hip/hip_runtime.h>
#include <hip/hip_bf16.h>
#include <float.h>

// MixMIL fused kernel set.
// Shapes (fixed by setup_inputs): I=512000, Q=128, P=1, S=8 (C=8 channels), N=4000.
// d_in: x[I,Q] f32, beta_u[Q,1,8] f32, beta_z[Q,1,8] f32, i[I] int32 (sorted), n_bags
// d_out: [N,1,8] f32.
//
// Algebra: eta = beta_z/b and out = b*(xmil-mean)/std. std scales linearly with
// the positive per-channel b, so accumulating with raw beta_z (v = x.beta_z)
// gives xmil' = b*xmil and b*(xmil'-mean')/std' == b*(xmil-mean)/std. We never
// form eta; b multiplies only at the very end.
//
// R2 changes vs R1 (latency-bound at 25% occupancy):
//  - bag boundaries precomputed once (mixmil_bounds) instead of a 2x19-step
//    dependent-load binary search per block
//  - 256-thread blocks, one bag per WAVE (4 bags/block): weights staged once
//    per 4 bags, and the 1-wave-workgroup scheduler throttle goes away
//  - stats kernel widened to 1024 threads

#define QDIM 128
#define C8 8

__device__ __forceinline__ void dot4(float& acc, const float4 a, const float4 b) {
    acc = fmaf(a.x, b.x, acc);
    acc = fmaf(a.y, b.y, acc);
    acc = fmaf(a.z, b.z, acc);
    acc = fmaf(a.w, b.w, acc);
}

// bag_start[j] = first index k with seg[k] >= j, for j in [0, N]; bag_start[N] = I.
__global__ void mixmil_bounds(const int* __restrict__ seg, int I, int N,
                              int* __restrict__ bs)
{
    int k = blockIdx.x * blockDim.x + threadIdx.x;
    if (k > I) return;
    int a    = (k < I) ? seg[k]     : N;
    int prev = (k > 0) ? seg[k - 1] : -1;
    for (int j = prev + 1; j <= a; ++j) bs[j] = k;
}

// 4 waves per block, one bag per wave. Online softmax + weighted sum, fused.
__global__ __launch_bounds__(256) void mixmil_bags(
    const float* __restrict__ x,
    const float* __restrict__ bu,
    const float* __restrict__ bz,
    const int*   __restrict__ bs,   // [N+1] bag boundaries
    int N,
    float* __restrict__ xmil)       // [N,8]
{
    __shared__ float WT[16][QDIM];  // rows 0..7: beta_u^T, rows 8..15: beta_z^T

    const int t = threadIdx.x;

    // Conflict-free staging: consecutive threads write consecutive q for fixed s.
    for (int j = t; j < QDIM * 16; j += 256) {
        int s = j >> 7, q = j & 127;
        WT[s][q] = (s < 8) ? bu[q * 8 + s] : bz[q * 8 + (s - 8)];
    }

    const int wave = t >> 6;
    const int lane = t & 63;
    const int n = blockIdx.x * 4 + wave;

    __syncthreads();
    if (n >= N) return;

    const int lo = bs[n];
    const int hi = bs[n + 1];

    // Per-thread online softmax state per channel: m (max), l (sum e), a (sum e*v)
    float mM[8], lL[8], aA[8];
#pragma unroll
    for (int c = 0; c < 8; ++c) { mM[c] = -1e30f; lL[c] = 0.f; aA[c] = 0.f; }

    // Lane handles rows lo+lane, lo+lane+64, stride 128 (2 rows in flight so the
    // LDS weight broadcasts amortize over 2 rows).
    for (int k = lo + lane; k < hi; k += 128) {
        const bool two = (k + 64) < hi;
        const float* xr1 = x + (long)k * QDIM;
        const float* xr2 = x + (long)(two ? (k + 64) : k) * QDIM;

        float du1[8], dv1[8], du2[8], dv2[8];
#pragma unroll
        for (int c = 0; c < 8; ++c) { du1[c] = dv1[c] = du2[c] = dv2[c] = 0.f; }

#pragma unroll 1
        for (int q0 = 0; q0 < QDIM; q0 += 16) {
            // 64B-granular per-lane loads: 4 consecutive float4 per row.
            float4 xa[4], xb[4];
#pragma unroll
            for (int j = 0; j < 4; ++j) {
                xa[j] = *(const float4*)(xr1 + q0 + 4 * j);
                xb[j] = *(const float4*)(xr2 + q0 + 4 * j);
            }
#pragma unroll
            for (int c = 0; c < 8; ++c) {
#pragma unroll
                for (int j = 0; j < 4; ++j) {
                    const float4 wu = *(const float4*)&WT[c][q0 + 4 * j];      // broadcast
                    const float4 wz = *(const float4*)&WT[8 + c][q0 + 4 * j];  // broadcast
                    dot4(du1[c], xa[j], wu);
                    dot4(dv1[c], xa[j], wz);
                    dot4(du2[c], xb[j], wu);
                    dot4(dv2[c], xb[j], wz);
                }
            }
        }

        // Online update, instance 1 then (if valid) instance 2.
#pragma unroll
        for (int c = 0; c < 8; ++c) {
            {
                float u = du1[c], v = dv1[c];
                float nm = fmaxf(mM[c], u);
                float sc = __expf(mM[c] - nm);
                float p  = __expf(u - nm);
                lL[c] = lL[c] * sc + p;
                aA[c] = aA[c] * sc + p * v;
                mM[c] = nm;
            }
            if (two) {
                float u = du2[c], v = dv2[c];
                float nm = fmaxf(mM[c], u);
                float sc = __expf(mM[c] - nm);
                float p  = __expf(u - nm);
                lL[c] = lL[c] * sc + p;
                aA[c] = aA[c] * sc + p * v;
                mM[c] = nm;
            }
        }
    }

    // Butterfly merge of online states across the 64 lanes of this wave.
    for (int off = 32; off; off >>= 1) {
#pragma unroll
        for (int c = 0; c < 8; ++c) {
            float m2 = __shfl_xor(mM[c], off);
            float l2 = __shfl_xor(lL[c], off);
            float a2 = __shfl_xor(aA[c], off);
            float nm = fmaxf(mM[c], m2);
            float s1 = __expf(mM[c] - nm);
            float s2 = __expf(m2 - nm);
            lL[c] = lL[c] * s1 + l2 * s2;
            aA[c] = aA[c] * s1 + a2 * s2;
            mM[c] = nm;
        }
    }

    if (lane == 0) {
        const bool nonempty = hi > lo;
#pragma unroll
        for (int c = 0; c < 8; ++c)
            xmil[(size_t)n * 8 + c] = nonempty ? (aA[c] / lL[c]) : 0.f;
    }
}

// Single block (1024 thr): per-channel mean/var (ddof=1) of xmil over bags,
// plus b = rms(beta_z). Deterministic. stats: [0..7]=b, [8..15]=mean, [16..23]=rstd.
__global__ __launch_bounds__(1024) void mixmil_stats(
    const float* __restrict__ xmil,
    const float* __restrict__ bz,
    int N,
    float* __restrict__ stats)
{
    double s[8], qq[8];
    float t2[8];
#pragma unroll
    for (int c = 0; c < 8; ++c) { s[c] = 0.0; qq[c] = 0.0; t2[c] = 0.f; }

    for (int r = threadIdx.x; r < N; r += 1024) {
        const float* row = xmil + (size_t)r * 8;
#pragma unroll
        for (int c = 0; c < 8; ++c) {
            float v = row[c];
            s[c] += v;
            qq[c] += (double)v * (double)v;
        }
    }
    for (int r = threadIdx.x; r < QDIM; r += 1024) {
        const float* row = bz + (size_t)r * 8;
#pragma unroll
        for (int c = 0; c < 8; ++c) { float v = row[c]; t2[c] = fmaf(v, v, t2[c]); }
    }

    // wave reduce (width 64)
    for (int off = 32; off; off >>= 1) {
#pragma unroll
        for (int c = 0; c < 8; ++c) {
            s[c]  += __shfl_xor(s[c], off);
            qq[c] += __shfl_xor(qq[c], off);
            t2[c] += __shfl_xor(t2[c], off);
        }
    }

    __shared__ double S[16][8], QQ[16][8];
    __shared__ float T2[16][8];
    const int w = threadIdx.x >> 6;
    if ((threadIdx.x & 63) == 0) {
#pragma unroll
        for (int c = 0; c < 8; ++c) { S[w][c] = s[c]; QQ[w][c] = qq[c]; T2[w][c] = t2[c]; }
    }
    __syncthreads();
    if (threadIdx.x == 0) {
#pragma unroll
        for (int c = 0; c < 8; ++c) {
            double ss = 0.0, qs = 0.0;
            float tt = 0.f;
#pragma unroll
            for (int w2 = 0; w2 < 16; ++w2) { ss += S[w2][c]; qs += QQ[w2][c]; tt += T2[w2][c]; }
            double mean = ss / (double)N;
            double var  = (qs - ss * ss / (double)N) / (double)(N - 1);
            stats[c]      = sqrtf(tt / (float)QDIM);   // b
            stats[8 + c]  = (float)mean;
            stats[16 + c] = (float)(1.0 / sqrt(var));  // rstd
        }
    }
}

__global__ void mixmil_out(
    const float* __restrict__ xmil,
    const float* __restrict__ stats,
    int total,
    float* __restrict__ out)
{
    int e = blockIdx.x * blockDim.x + threadIdx.x;
    if (e >= total) return;
    int c = e & 7;
    out[e] = stats[c] * (xmil[e] - stats[8 + c]) * stats[16 + c];
}

extern "C" void kernel_launch(void* const* d_in, const int* in_sizes, int n_in,
                              void* d_out, int out_size, void* d_ws, size_t ws_size,
                              hipStream_t stream) {
    const float* x  = (const float*)d_in[0];
    const float* bu = (const float*)d_in[1];
    const float* bz = (const float*)d_in[2];
    const int*   sg = (const int*)d_in[3];   // sorted bag ids (int32)

    const int I = in_sizes[0] / QDIM;        // 512000
    const int N = out_size / C8;             // 4000 bags

    float* xmil  = (float*)d_ws;             // [N,8]
    float* stats = xmil + (size_t)N * C8;    // 24 floats
    int*   bs    = (int*)(stats + 32);       // [N+1] bag boundaries

    mixmil_bounds<<<(I + 256) / 256, 256, 0, stream>>>(sg, I, N, bs);

    const int nblk = (N + 3) / 4;
    mixmil_bags<<<nblk, 256, 0, stream>>>(x, bu, bz, bs, N, xmil);

    mixmil_stats<<<1, 1024, 0, stream>>>(xmil, bz, N, stats);

    const int total = N * C8;
    mixmil_out<<<(total + 255) / 256, 256, 0, stream>>>(
        xmil, stats, total, (float*)d_out);
}

// Round 6
// 118.584 us; speedup vs baseline: 2.7039x; 1.1862x over previous
//
#include <hip/hip_runtime.h>
#include <hip/hip_bf16.h>
#include <float.h>

// MixMIL fused kernel set.
// Shapes (fixed by setup_inputs): I=512000, Q=128, P=1, S=8 (C=8 channels), N=4000.
// d_in: x[I,Q] f32, beta_u[Q,1,8] f32, beta_z[Q,1,8] f32, i[I] int32 (sorted), n_bags
// d_out: [N,1,8] f32.
//
// Algebra: eta = beta_z/b and out = b*(xmil-mean)/std. std scales linearly with
// the positive per-channel b, so accumulating with raw beta_z (v = x.beta_z)
// gives xmil' = b*xmil and b*(xmil'-mean')/std' == b*(xmil-mean)/std. b only
// multiplies at the very end.
//
// R3 restructure (R2 was latency-bound at 22% occupancy, all pipes <32%):
//  - Pass 1 (mixmil_proj): pure streaming kernel over x -> uz[I,16]
//    (u=x.beta_u, z=x.beta_z). Register-pipelined loads, no bag coupling.
//  - Pass 2 (mixmil_bags2): per-bag-per-wave online softmax over uz (64 B/row,
//    L2/L3-hot) instead of x (512 B/row from HBM).
// (R5 = R3 resubmitted again: R4 and R5 benches both died to the same
//  unresponsive container before running; the kernel itself was never measured.)

#define QDIM 128
#define C8 8

__device__ __forceinline__ void dot4(float& acc, const float4 a, const float4 b) {
    acc = fmaf(a.x, b.x, acc);
    acc = fmaf(a.y, b.y, acc);
    acc = fmaf(a.z, b.z, acc);
    acc = fmaf(a.w, b.w, acc);
}

// bag_start[j] = first index k with seg[k] >= j, for j in [0, N]; bs[N] = I.
__global__ void mixmil_bounds(const int* __restrict__ seg, int I, int N,
                              int* __restrict__ bs)
{
    int k = blockIdx.x * blockDim.x + threadIdx.x;
    if (k > I) return;
    int a    = (k < I) ? seg[k]     : N;
    int prev = (k > 0) ? seg[k - 1] : -1;
    for (int j = prev + 1; j <= a; ++j) bs[j] = k;
}

// Pass 1: uz[r][0..7] = x[r].beta_u[:,c], uz[r][8..15] = x[r].beta_z[:,c].
// Thread g handles rows g and g+halfI. Explicit 2-stage load pipeline.
__global__ __launch_bounds__(256) void mixmil_proj(
    const float* __restrict__ x,
    const float* __restrict__ bu,
    const float* __restrict__ bz,
    int halfI,
    float* __restrict__ uz)
{
    __shared__ float WT[16][QDIM];  // rows 0..7: beta_u^T, rows 8..15: beta_z^T

    const int t = threadIdx.x;
    for (int j = t; j < QDIM * 16; j += 256) {
        int s = j >> 7, q = j & 127;
        WT[s][q] = (s < 8) ? bu[q * 8 + s] : bz[q * 8 + (s - 8)];
    }

    const int g = blockIdx.x * 256 + t;
    __syncthreads();
    if (g >= halfI) return;

    const float* xr1 = x + (size_t)g * QDIM;
    const float* xr2 = xr1 + (size_t)halfI * QDIM;

    float du1[8], dv1[8], du2[8], dv2[8];
#pragma unroll
    for (int c = 0; c < 8; ++c) { du1[c] = dv1[c] = du2[c] = dv2[c] = 0.f; }

    float4 A0[4], B0[4], A1[4], B1[4];
#pragma unroll
    for (int j = 0; j < 4; ++j) {
        A0[j] = *(const float4*)(xr1 + 4 * j);
        B0[j] = *(const float4*)(xr2 + 4 * j);
    }

#pragma unroll
    for (int q0 = 0; q0 < QDIM; q0 += 16) {
        // prefetch next chunk while computing current
        if (q0 + 16 < QDIM) {
#pragma unroll
            for (int j = 0; j < 4; ++j) {
                A1[j] = *(const float4*)(xr1 + q0 + 16 + 4 * j);
                B1[j] = *(const float4*)(xr2 + q0 + 16 + 4 * j);
            }
        }
#pragma unroll
        for (int c = 0; c < 8; ++c) {
#pragma unroll
            for (int j = 0; j < 4; ++j) {
                const float4 wu = *(const float4*)&WT[c][q0 + 4 * j];      // broadcast
                const float4 wz = *(const float4*)&WT[8 + c][q0 + 4 * j];  // broadcast
                dot4(du1[c], A0[j], wu);
                dot4(dv1[c], A0[j], wz);
                dot4(du2[c], B0[j], wu);
                dot4(dv2[c], B0[j], wz);
            }
        }
#pragma unroll
        for (int j = 0; j < 4; ++j) { A0[j] = A1[j]; B0[j] = B1[j]; }
    }

    float4* o1 = (float4*)(uz + (size_t)g * 16);
    float4* o2 = (float4*)(uz + ((size_t)g + halfI) * 16);
    o1[0] = make_float4(du1[0], du1[1], du1[2], du1[3]);
    o1[1] = make_float4(du1[4], du1[5], du1[6], du1[7]);
    o1[2] = make_float4(dv1[0], dv1[1], dv1[2], dv1[3]);
    o1[3] = make_float4(dv1[4], dv1[5], dv1[6], dv1[7]);
    o2[0] = make_float4(du2[0], du2[1], du2[2], du2[3]);
    o2[1] = make_float4(du2[4], du2[5], du2[6], du2[7]);
    o2[2] = make_float4(dv2[0], dv2[1], dv2[2], dv2[3]);
    o2[3] = make_float4(dv2[4], dv2[5], dv2[6], dv2[7]);
}

// Pass 2: one bag per wave, online softmax + weighted sum over uz rows.
__global__ __launch_bounds__(256) void mixmil_bags2(
    const float* __restrict__ uz,
    const int*   __restrict__ bs,
    int N,
    float* __restrict__ xmil)  // [N,8]
{
    const int wave = threadIdx.x >> 6;
    const int lane = threadIdx.x & 63;
    const int n = blockIdx.x * 4 + wave;
    if (n >= N) return;

    const int lo = bs[n];
    const int hi = bs[n + 1];

    float mM[8], lL[8], aA[8];
#pragma unroll
    for (int c = 0; c < 8; ++c) { mM[c] = -1e30f; lL[c] = 0.f; aA[c] = 0.f; }

    for (int k = lo + lane; k < hi; k += 64) {
        const float4* r = (const float4*)(uz + (size_t)k * 16);
        float4 u0 = r[0], u1 = r[1], v0 = r[2], v1 = r[3];
        float uu[8] = {u0.x, u0.y, u0.z, u0.w, u1.x, u1.y, u1.z, u1.w};
        float vv[8] = {v0.x, v0.y, v0.z, v0.w, v1.x, v1.y, v1.z, v1.w};
#pragma unroll
        for (int c = 0; c < 8; ++c) {
            float u = uu[c], v = vv[c];
            float nm = fmaxf(mM[c], u);
            float sc = __expf(mM[c] - nm);
            float p  = __expf(u - nm);
            lL[c] = lL[c] * sc + p;
            aA[c] = aA[c] * sc + p * v;
            mM[c] = nm;
        }
    }

    // Butterfly merge across the 64 lanes of this wave.
    for (int off = 32; off; off >>= 1) {
#pragma unroll
        for (int c = 0; c < 8; ++c) {
            float m2 = __shfl_xor(mM[c], off);
            float l2 = __shfl_xor(lL[c], off);
            float a2 = __shfl_xor(aA[c], off);
            float nm = fmaxf(mM[c], m2);
            float s1 = __expf(mM[c] - nm);
            float s2 = __expf(m2 - nm);
            lL[c] = lL[c] * s1 + l2 * s2;
            aA[c] = aA[c] * s1 + a2 * s2;
            mM[c] = nm;
        }
    }

    if (lane == 0) {
        const bool nonempty = hi > lo;
#pragma unroll
        for (int c = 0; c < 8; ++c)
            xmil[(size_t)n * 8 + c] = nonempty ? (aA[c] / lL[c]) : 0.f;
    }
}

// Single block (1024 thr): per-channel mean/var (ddof=1) of xmil over bags,
// plus b = rms(beta_z). Deterministic. stats: [0..7]=b, [8..15]=mean, [16..23]=rstd.
__global__ __launch_bounds__(1024) void mixmil_stats(
    const float* __restrict__ xmil,
    const float* __restrict__ bz,
    int N,
    float* __restrict__ stats)
{
    double s[8], qq[8];
    float t2[8];
#pragma unroll
    for (int c = 0; c < 8; ++c) { s[c] = 0.0; qq[c] = 0.0; t2[c] = 0.f; }

    for (int r = threadIdx.x; r < N; r += 1024) {
        const float* row = xmil + (size_t)r * 8;
#pragma unroll
        for (int c = 0; c < 8; ++c) {
            float v = row[c];
            s[c] += v;
            qq[c] += (double)v * (double)v;
        }
    }
    for (int r = threadIdx.x; r < QDIM; r += 1024) {
        const float* row = bz + (size_t)r * 8;
#pragma unroll
        for (int c = 0; c < 8; ++c) { float v = row[c]; t2[c] = fmaf(v, v, t2[c]); }
    }

    for (int off = 32; off; off >>= 1) {
#pragma unroll
        for (int c = 0; c < 8; ++c) {
            s[c]  += __shfl_xor(s[c], off);
            qq[c] += __shfl_xor(qq[c], off);
            t2[c] += __shfl_xor(t2[c], off);
        }
    }

    __shared__ double S[16][8], QQ[16][8];
    __shared__ float T2[16][8];
    const int w = threadIdx.x >> 6;
    if ((threadIdx.x & 63) == 0) {
#pragma unroll
        for (int c = 0; c < 8; ++c) { S[w][c] = s[c]; QQ[w][c] = qq[c]; T2[w][c] = t2[c]; }
    }
    __syncthreads();
    if (threadIdx.x == 0) {
#pragma unroll
        for (int c = 0; c < 8; ++c) {
            double ss = 0.0, qs = 0.0;
            float tt = 0.f;
#pragma unroll
            for (int w2 = 0; w2 < 16; ++w2) { ss += S[w2][c]; qs += QQ[w2][c]; tt += T2[w2][c]; }
            double mean = ss / (double)N;
            double var  = (qs - ss * ss / (double)N) / (double)(N - 1);
            stats[c]      = sqrtf(tt / (float)QDIM);   // b
            stats[8 + c]  = (float)mean;
            stats[16 + c] = (float)(1.0 / sqrt(var));  // rstd
        }
    }
}

__global__ void mixmil_out(
    const float* __restrict__ xmil,
    const float* __restrict__ stats,
    int total,
    float* __restrict__ out)
{
    int e = blockIdx.x * blockDim.x + threadIdx.x;
    if (e >= total) return;
    int c = e & 7;
    out[e] = stats[c] * (xmil[e] - stats[8 + c]) * stats[16 + c];
}

extern "C" void kernel_launch(void* const* d_in, const int* in_sizes, int n_in,
                              void* d_out, int out_size, void* d_ws, size_t ws_size,
                              hipStream_t stream) {
    const float* x  = (const float*)d_in[0];
    const float* bu = (const float*)d_in[1];
    const float* bz = (const float*)d_in[2];
    const int*   sg = (const int*)d_in[3];   // sorted bag ids (int32)

    const int I = in_sizes[0] / QDIM;        // 512000
    const int N = out_size / C8;             // 4000 bags
    const int halfI = I / 2;                 // I is even (512000)

    // ws layout: uz[I*16] | xmil[N*8] | stats[32] | bs[N+1]   (ws ~1 GB, 33 MB used)
    float* uz    = (float*)d_ws;
    float* xmil  = uz + (size_t)I * 16;
    float* stats = xmil + (size_t)N * C8;
    int*   bs    = (int*)(stats + 32);

    mixmil_bounds<<<(I + 256) / 256, 256, 0, stream>>>(sg, I, N, bs);

    mixmil_proj<<<(halfI + 255) / 256, 256, 0, stream>>>(x, bu, bz, halfI, uz);

    mixmil_bags2<<<(N + 3) / 4, 256, 0, stream>>>(uz, bs, N, xmil);

    mixmil_stats<<<1, 1024, 0, stream>>>(xmil, bz, N, stats);

    const int total = N * C8;
    mixmil_out<<<(total + 255) / 256, 256, 0, stream>>>(
        xmil, stats, total, (float*)d_out);
}